// Round 10
// baseline (325.605 us; speedup 1.0000x reference)
//
#include <hip/hip_runtime.h>
#include <hip/hip_bf16.h>

typedef __bf16 bf16_t;
typedef __bf16 bf16x8 __attribute__((ext_vector_type(8)));
typedef float  f32x4  __attribute__((ext_vector_type(4)));

#define T_LEN 200
#define D_DIM 256
#define NT    13      // 16-row tiles
#define ROWS  208

__device__ __forceinline__ float fast_tanh(float x) {
    float e = __expf(2.0f * x);
    return 1.0f - 2.0f / (e + 1.0f);
}

// async global->LDS DMA, 16 B/lane; LDS dest = wave-uniform base + lane*16
__device__ __forceinline__ void gload_lds16(const float* g, char* l) {
    __builtin_amdgcn_global_load_lds(
        (const __attribute__((address_space(1))) unsigned int*)g,
        (__attribute__((address_space(3))) unsigned int*)l,
        16, 0, 0);
}

// ---------------------------------------------------------------------------
// Kernel 1a: qpart[b][d] = sum_k Q[b][k] * W1[d][k]  (f32) -> d_out (scratch)
// ---------------------------------------------------------------------------
__global__ __launch_bounds__(256) void qpart_kernel(
    const float* __restrict__ Q, const float* __restrict__ W1,
    float* __restrict__ Out)
{
    __shared__ float qs[8][256];
    const int tid = threadIdx.x;
    const int b0  = blockIdx.x * 8;
    for (int idx = tid; idx < 8 * 256; idx += 256)
        qs[idx >> 8][idx & 255] = Q[(size_t)(b0 + (idx >> 8)) * 256 + (idx & 255)];
    __syncthreads();
    float acc[8];
    #pragma unroll
    for (int i = 0; i < 8; ++i) acc[i] = 0.f;
    const f32x4* Wv = (const f32x4*)(W1 + (size_t)tid * 512);
    #pragma unroll 4
    for (int k4 = 0; k4 < 64; ++k4) {
        f32x4 w = Wv[k4];
        #pragma unroll
        for (int bb = 0; bb < 8; ++bb) {
            f32x4 qv = *(const f32x4*)&qs[bb][k4 * 4];
            acc[bb] += qv[0]*w[0] + qv[1]*w[1] + qv[2]*w[2] + qv[3]*w[3];
        }
    }
    #pragma unroll
    for (int bb = 0; bb < 8; ++bb)
        Out[(size_t)(b0 + bb) * 256 + tid] = acc[bb];
}

// ---------------------------------------------------------------------------
// Kernel 1b: W1b (= W1[:,256:512]) -> bf16, row-major [256][256] in ws.
// ---------------------------------------------------------------------------
__global__ __launch_bounds__(256) void convw_kernel(
    const float* __restrict__ W1, bf16_t* __restrict__ bfW)
{
    const int d = blockIdx.x;
    const int k = threadIdx.x;
    bfW[(size_t)d * 256 + k] = (bf16_t)W1[(size_t)d * 512 + 256 + k];
}

// ---------------------------------------------------------------------------
// Kernel 2 (v10): one batch per block, m97-style counted-vmcnt pipeline.
// 16-row f32 tiles, triple-buffered, staged by global_load_lds (2 row-DMAs
// per wave per tile). Steady state: compute tile i while tiles i+1, i+2 in
// flight; after PV of tile i, issue tile i+3 into the freed buffer and
// s_waitcnt vmcnt(4) (never 0 until the tail). Scores (swapped-operand MFMA,
// in-lane W2-dot) and PV (f32, exact) are fused per tile — no re-reads.
// No-max softmax: |s| <= ||W2||_1 ~ 13 => p = exp(s) directly.
// Source-chunk XOR swizzle (chunk c = lane ^ (r&7)) on the DMA source, same
// XOR on every LDS read (both-sides involution, rule #21).
// ---------------------------------------------------------------------------
template<bool BFW>
__global__ __launch_bounds__(512, 4) void attn_v10_kernel(
    const float* __restrict__ U,      // [B,200,256]
    const int*   __restrict__ Mask,   // [B,200]
    const float* __restrict__ W1,     // [256,512] (BFW=false frag source)
    const float* __restrict__ W2,     // [256]
    const bf16_t* __restrict__ bfW,   // [256][256] bf16 W1b (BFW=true)
    float* Out)                       // qpart on entry; final out on exit
{
    __shared__ char  tiles[3][16384];   // 48 KB: three 16x256 f32 tiles
    __shared__ float score_lds[ROWS];
    __shared__ int   msk_lds[ROWS];     // 0 normal, 1 masked, 2 pad
    __shared__ float out_half[2][256];
    __shared__ float l_red;

    const int tid  = threadIdx.x;
    const int lane = tid & 63;
    const int wv   = tid >> 6;   // wave 0..7 -> d block [wv*32, wv*32+32)
    const int lr   = lane & 15;
    const int lg   = lane >> 4;
    const int b    = blockIdx.x;
    const float* Ub = U + (size_t)b * (T_LEN * D_DIM);

    if (tid < ROWS) {
        score_lds[tid] = 0.f;
        msk_lds[tid] = (tid < T_LEN) ? (Mask[(size_t)b * T_LEN + tid] ? 1 : 0) : 2;
    }
    if (tid == 0) l_red = 0.f;

    // stage tile tt into LDS slot: each wave DMAs rows wv*2, wv*2+1
    auto stage_tile = [&](int tt, int slot) {
        #pragma unroll
        for (int k = 0; k < 2; ++k) {
            const int r = wv * 2 + k;
            int t = tt * 16 + r; if (t > T_LEN - 1) t = T_LEN - 1;  // clamp pads
            const unsigned c = (unsigned)lane ^ ((unsigned)r & 7u);
            gload_lds16(Ub + (size_t)t * 256 + c * 4, &tiles[slot][r * 1024]);
        }
    };

    // prologue: fill the 3-deep pipeline
    stage_tile(0, 0);
    stage_tile(1, 1);
    stage_tile(2, 2);

    // A-fragments: W1b rows d = wv*32 + sub*16 + lr  (issued under DMA latency)
    bf16x8 aw[2][8];
    #pragma unroll
    for (int sub = 0; sub < 2; ++sub) {
        const int d = wv * 32 + sub * 16 + lr;
        if (BFW) {
            #pragma unroll
            for (int kk = 0; kk < 8; ++kk)
                aw[sub][kk] = *(const bf16x8*)(bfW + (size_t)d * 256 + kk * 32 + lg * 8);
        } else {
            const float* wrow = W1 + (size_t)d * 512 + 256;
            #pragma unroll
            for (int kk = 0; kk < 8; ++kk) {
                const float* s = wrow + kk * 32 + lg * 8;
                f32x4 lo = *(const f32x4*)s;
                f32x4 hi = *(const f32x4*)(s + 4);
                bf16x8 v;
                v[0]=(bf16_t)lo[0]; v[1]=(bf16_t)lo[1]; v[2]=(bf16_t)lo[2]; v[3]=(bf16_t)lo[3];
                v[4]=(bf16_t)hi[0]; v[5]=(bf16_t)hi[1]; v[6]=(bf16_t)hi[2]; v[7]=(bf16_t)hi[3];
                aw[sub][kk] = v;
            }
        }
    }
    float w2v[2][4], qpv[2][4];
    #pragma unroll
    for (int sub = 0; sub < 2; ++sub)
        #pragma unroll
        for (int r = 0; r < 4; ++r) {
            const int d = wv * 32 + sub * 16 + lg * 4 + r;
            w2v[sub][r] = W2[d];
            qpv[sub][r] = Out[(size_t)b * 256 + d];   // qpart (pre-overwrite)
        }

    asm volatile("s_waitcnt vmcnt(0)" ::: "memory");   // tiles 0-2 + frags done
    __syncthreads();

    float o_acc = 0.f;
    const int c_col = tid & 255;   // output column owned by this thread
    const int hf    = tid >> 8;    // row-half (j 0-7 vs 8-15)

    int slot = 0;
    for (int i = 0; i < NT; ++i) {
        char* const buf = tiles[slot];

        // ---- scores: C[row=d][col=t], W2-dot in-lane ----
        f32x4 a0 = {qpv[0][0], qpv[0][1], qpv[0][2], qpv[0][3]};
        f32x4 a1 = {qpv[1][0], qpv[1][1], qpv[1][2], qpv[1][3]};
        {
            const char* rowp = buf + lr * 1024;
            const unsigned rsw = (unsigned)lr & 7u;
            #pragma unroll
            for (int kk = 0; kk < 8; ++kk) {
                const unsigned q0 = (unsigned)(kk * 8 + lg * 2);
                f32x4 x0 = *(const f32x4*)(rowp + ((q0 ^ rsw) << 4));
                f32x4 x1 = *(const f32x4*)(rowp + (((q0 + 1) ^ rsw) << 4));
                bf16x8 u;
                u[0]=(bf16_t)x0[0]; u[1]=(bf16_t)x0[1]; u[2]=(bf16_t)x0[2]; u[3]=(bf16_t)x0[3];
                u[4]=(bf16_t)x1[0]; u[5]=(bf16_t)x1[1]; u[6]=(bf16_t)x1[2]; u[7]=(bf16_t)x1[3];
                a0 = __builtin_amdgcn_mfma_f32_16x16x32_bf16(aw[0][kk], u, a0, 0, 0, 0);
                a1 = __builtin_amdgcn_mfma_f32_16x16x32_bf16(aw[1][kk], u, a1, 0, 0, 0);
            }
        }
        {
            float s = 0.f;
            #pragma unroll
            for (int r = 0; r < 4; ++r) {
                s += w2v[0][r] * fast_tanh(a0[r]);
                s += w2v[1][r] * fast_tanh(a1[r]);
            }
            s += __shfl_xor(s, 16);
            s += __shfl_xor(s, 32);
            if (lg == 0) atomicAdd(&score_lds[i * 16 + lr], s);
        }
        __syncthreads();   // scores[i] ready; all MFMA reads of buf done

        // ---- PV: p = exp(masked s), o += p * u  (f32, exact) ----
        {
            const int jb = i * 16 + hf * 8;
            #pragma unroll
            for (int jj = 0; jj < 8; ++jj) {
                const int j    = hf * 8 + jj;
                const int code = msk_lds[jb + jj];
                const float sc = score_lds[jb + jj];
                const float p  = (code == 0) ? __expf(sc) : (code == 1 ? 1.f : 0.f);
                const unsigned byt = (unsigned)j * 1024
                    + ((((unsigned)c_col >> 2) ^ ((unsigned)j & 7u)) << 4)
                    + ((unsigned)c_col & 3u) * 4;
                o_acc += p * *(const float*)(buf + byt);
            }
        }
        __syncthreads();   // PV reads done -> buf free for tile i+3

        if (i < NT - 1) {
            if (i + 3 < NT) stage_tile(i + 3, slot);
            // counted waits: tile i+1 must be complete (2 DMAs per tile/wave)
            if (i < 10)       asm volatile("s_waitcnt vmcnt(4)" ::: "memory");
            else if (i == 10) asm volatile("s_waitcnt vmcnt(2)" ::: "memory");
            else              asm volatile("s_waitcnt vmcnt(0)" ::: "memory");
            __syncthreads();   // everyone's tile i+1 landed
        }
        slot = (slot == 2) ? 0 : slot + 1;
    }

    // ---- epilogue: combine halves, denominator, write ----
    out_half[hf][c_col] = o_acc;
    float lp = 0.f;
    if (tid < ROWS) {
        const int code = msk_lds[tid];
        lp = (code == 0) ? __expf(score_lds[tid]) : (code == 1 ? 1.f : 0.f);
    }
    lp += __shfl_xor(lp, 1);
    lp += __shfl_xor(lp, 2);
    lp += __shfl_xor(lp, 4);
    lp += __shfl_xor(lp, 8);
    lp += __shfl_xor(lp, 16);
    lp += __shfl_xor(lp, 32);
    if (lane == 0 && lp != 0.f) atomicAdd(&l_red, lp);
    __syncthreads();
    if (tid < 256)
        Out[(size_t)b * 256 + tid] = (out_half[0][tid] + out_half[1][tid]) / l_red;
}

extern "C" void kernel_launch(void* const* d_in, const int* in_sizes, int n_in,
                              void* d_out, int out_size, void* d_ws, size_t ws_size,
                              hipStream_t stream)
{
    const float* Q  = (const float*)d_in[0];
    const float* U  = (const float*)d_in[1];
    const int*   Mk = (const int*)d_in[2];
    const float* W1 = (const float*)d_in[3];
    const float* W2 = (const float*)d_in[4];
    float* Out = (float*)d_out;
    const int B = in_sizes[0] / D_DIM;   // 2048

    qpart_kernel<<<dim3(B / 8), dim3(256), 0, stream>>>(Q, W1, Out);

    if (ws_size >= (size_t)256 * 256 * 2) {
        bf16_t* bfw = (bf16_t*)d_ws;
        convw_kernel<<<dim3(256), dim3(256), 0, stream>>>(W1, bfw);
        attn_v10_kernel<true><<<dim3(B), dim3(512), 0, stream>>>(
            U, Mk, W1, W2, bfw, Out);
    } else {
        attn_v10_kernel<false><<<dim3(B), dim3(512), 0, stream>>>(
            U, Mk, W1, W2, nullptr, Out);
    }
}